// Round 1
// baseline (331.048 us; speedup 1.0000x reference)
//
#include <hip/hip_runtime.h>
#include <math.h>

#define B_ 4
#define T_ 128
#define V_ 50257
#define D_ 512
#define NROWS 512           // B*T
#define GAMMA2_ 0.1f

// ---------------- old fused path (fallback) ----------------
#define BK 32
#define KC 1600             // k per split (multiple of BK)
#define SPLITK 32           // 32*1600 = 51200 >= 50257
#define NIT (KC / BK)
#define LDA 40
#define LDB 40
#define SLICE (NROWS * D_)  // floats per slice
#define WS_PART_OFF 1024

// ---------------- new bf16 path ----------------
#define SPLITK2 48
#define KC2 1056            // 48*1056 = 50688 >= 50257
#define KP 50688            // padded K; rows 16B-aligned (KP*2 % 16 == 0)
#define NXB 2048            // X-prep blocks
#define NWB ((KP / 64) * (D_ / 64))   // 792*8 = 6336 W-transpose tiles
#define ACC_BYTES 4096
#define XB_BYTES ((size_t)NROWS * KP * 2)
#define WT_BYTES ((size_t)D_ * KP * 2)
#define PART2_BYTES ((size_t)SPLITK2 * SLICE * 4)
#define NEED_NEW (ACC_BYTES + XB_BYTES + WT_BYTES + PART2_BYTES)

typedef __attribute__((ext_vector_type(8))) short s8v;     // 8 bf16 (4 VGPRs)
typedef __attribute__((ext_vector_type(4))) float f4v;     // MFMA C/D

__device__ inline unsigned int pack2bf(float f0, float f1) {
    unsigned int u0 = __float_as_uint(f0);
    unsigned int u1 = __float_as_uint(f1);
    u0 += 0x7fffu + ((u0 >> 16) & 1u);
    u1 += 0x7fffu + ((u1 >> 16) & 1u);
    return (u0 >> 16) | (u1 & 0xffff0000u);
}

// LDS-only barrier (old path): waits lgkmcnt(0), leaves vmcnt in flight.
__device__ inline void sync_lds() {
    __builtin_amdgcn_s_waitcnt(0xC07F);
    __builtin_amdgcn_s_barrier();
}

__device__ inline float wave_reduce(float v) {
    #pragma unroll
    for (int o = 32; o > 0; o >>= 1) v += __shfl_down(v, o, 64);
    return v;
}

// async global->LDS, 16B per lane; lds dest = wave-uniform base + lane*16
__device__ __forceinline__ void gload16(const unsigned short* g, unsigned short* l) {
    __builtin_amdgcn_global_load_lds(
        (const __attribute__((address_space(1))) unsigned int*)g,
        (__attribute__((address_space(3))) unsigned int*)l, 16, 0, 0);
}

// ---------------- misc body: nll, coverage, dec_len sums ----------------
__device__ void misc_body(int bid,
                          const float* __restrict__ output_mle,
                          const float* __restrict__ attn,
                          const float* __restrict__ cover,
                          const int* __restrict__ trg,
                          const int* __restrict__ dec_mask,
                          const int* __restrict__ dec_len,
                          float* __restrict__ acc) {
    if (bid < 64) {
        float s = 0.f;
        const float4* a4 = (const float4*)attn;
        const float4* c4 = (const float4*)cover;
        for (int i4 = bid * 256 + threadIdx.x; i4 < 65536; i4 += 64 * 256) {
            float4 a = a4[i4];
            float4 c = c4[i4];
            int b = i4 >> 14;
            int t = (i4 << 2) & (T_ - 1);
            int4 m = *(const int4*)&dec_mask[(b << 7) + t];
            s += m.x ? 0.f : fminf(a.x, c.x);
            s += m.y ? 0.f : fminf(a.y, c.y);
            s += m.z ? 0.f : fminf(a.z, c.z);
            s += m.w ? 0.f : fminf(a.w, c.w);
        }
        s = wave_reduce(s);
        if ((threadIdx.x & 63) == 0) atomicAdd(&acc[2], s);
    } else {
        float lp = 0.f, cnt = 0.f;
        for (int i = threadIdx.x; i < NROWS; i += 256) {
            int tg = trg[i];
            if (tg != 0) {
                lp += __logf(output_mle[(size_t)i * V_ + tg]);
                cnt += 1.f;
            }
        }
        lp = wave_reduce(lp); cnt = wave_reduce(cnt);
        if ((threadIdx.x & 63) == 0) { atomicAdd(&acc[0], lp); atomicAdd(&acc[1], cnt); }
        if (threadIdx.x < B_) atomicAdd(&acc[3], (float)dec_len[threadIdx.x]);
    }
}

__global__ void misc_kernel(const float* __restrict__ output_mle,
                            const float* __restrict__ attn,
                            const float* __restrict__ cover,
                            const int* __restrict__ trg,
                            const int* __restrict__ dec_mask,
                            const int* __restrict__ dec_len,
                            float* __restrict__ acc) {
    misc_body(blockIdx.x, output_mle, attn, cover, trg, dec_mask, dec_len, acc);
}

// ---------------- prep: Xb = bf16(exp(X)) padded; Wt = bf16(W^T) padded; + misc ----
__launch_bounds__(256)
__global__ void prep_kernel(const float* __restrict__ X,
                            const float* __restrict__ W,
                            const float* __restrict__ attn,
                            const float* __restrict__ cover,
                            const int* __restrict__ trg,
                            const int* __restrict__ dec_mask,
                            const int* __restrict__ dec_len,
                            float* __restrict__ acc,
                            unsigned short* __restrict__ Xb,
                            unsigned short* __restrict__ Wt) {
    const int bid = blockIdx.x;
    const int tid = threadIdx.x;
    if (bid < NXB) {
        // X: exp + bf16, zero-pad [V_, KP). 8 output elems per unit.
        const int upr = KP / 8;               // units per row = 6336
        for (int u = bid * 256 + tid; u < NROWS * upr; u += NXB * 256) {
            int row = u / upr;
            int k8  = (u - row * upr) * 8;
            const float* src = X + (size_t)row * V_ + k8;
            unsigned int pk[4];
            if (k8 + 8 <= V_) {
                float e[8];
                #pragma unroll
                for (int j = 0; j < 8; j++) e[j] = __expf(src[j]);
                #pragma unroll
                for (int p = 0; p < 4; p++) pk[p] = pack2bf(e[2 * p], e[2 * p + 1]);
            } else {
                #pragma unroll
                for (int p = 0; p < 4; p++) {
                    float e0 = (k8 + 2 * p     < V_) ? __expf(src[2 * p])     : 0.f;
                    float e1 = (k8 + 2 * p + 1 < V_) ? __expf(src[2 * p + 1]) : 0.f;
                    pk[p] = pack2bf(e0, e1);
                }
            }
            *(uint4*)&Xb[(size_t)row * KP + k8] = *(uint4*)pk;
        }
    } else if (bid < NXB + NWB) {
        // W transpose tile 64(k) x 64(d) via LDS; write 128B-contiguous bf16 rows.
        __shared__ float Ls[64][64];
        int w  = bid - NXB;
        int kt = w >> 3;
        int dt = w & 7;
        int k0 = kt << 6, d0 = dt << 6;
        int r0 = tid >> 4;
        int c0 = (tid & 15) << 2;
        #pragma unroll
        for (int q = 0; q < 4; q++) {
            int r  = (q << 4) + r0;
            int gk = k0 + r;
            float4 v;
            if (gk < V_) v = *(const float4*)&W[(size_t)gk * D_ + d0 + c0];
            else         v = make_float4(0.f, 0.f, 0.f, 0.f);
            *(float4*)&Ls[r][c0] = v;
        }
        __syncthreads();
        int d  = tid >> 2;
        int kc = (tid & 3) << 4;
        unsigned int pk[8];
        #pragma unroll
        for (int p = 0; p < 8; p++)
            pk[p] = pack2bf(Ls[kc + 2 * p][d], Ls[kc + 2 * p + 1][d]);
        unsigned short* dst = Wt + (size_t)(d0 + d) * KP + k0 + kc;
        *(uint4*)&dst[0] = *(uint4*)&pk[0];
        *(uint4*)&dst[8] = *(uint4*)&pk[4];
    } else {
        misc_body(bid - (NXB + NWB), X, attn, cover, trg, dec_mask, dec_len, acc);
    }
}

// ---------------- gemm2: pure-bf16 m97-structure, global_load_lds, no masking ----
__launch_bounds__(256)
__global__ void gemm2_kernel(const unsigned short* __restrict__ Xb,
                             const unsigned short* __restrict__ Wt,
                             float* __restrict__ part) {
    __shared__ __align__(16) unsigned short As[128 * 32];  // [row][k] 8KB
    __shared__ __align__(16) unsigned short Bs[128 * 32];  // [col][k] 8KB

    const int bx   = blockIdx.x;
    const int tile = bx & 15;
    const int s    = bx >> 4;
    const int i0   = (tile & 3) * 128;
    const int d0   = (tile >> 2) * 128;
    const size_t ks = (size_t)s * KC2;

    const int tid  = threadIdx.x;
    const int lane = tid & 63;
    const int wave = tid >> 6;
    const int wm   = (wave & 1) * 64;
    const int wn   = (wave >> 1) * 64;
    const int l15  = lane & 15;
    const int l4   = lane >> 4;

    // gload mapping: lane -> (row = wave*16 + lane/4, kchunk = (lane&3)*8)
    const int grow = wave * 16 + (lane >> 2);
    const int gk8  = (lane & 3) * 8;
    const unsigned short* gA0 = Xb + (size_t)(i0 + grow) * KP + ks + gk8;
    const unsigned short* gA1 = gA0 + (size_t)64 * KP;
    const unsigned short* gB0 = Wt + (size_t)(d0 + grow) * KP + ks + gk8;
    const unsigned short* gB1 = gB0 + (size_t)64 * KP;
    unsigned short* lA = As + wave * 512;   // wave-uniform dest base
    unsigned short* lB = Bs + wave * 512;

    f4v acc[4][4];
    #pragma unroll
    for (int a = 0; a < 4; a++)
        #pragma unroll
        for (int b = 0; b < 4; b++) acc[a][b] = (f4v)0.f;

    #pragma unroll 1
    for (int kk = 0; kk < KC2; kk += 32) {
        __syncthreads();                       // prev compute done: LDS reusable
        gload16(gA0 + kk, lA);
        gload16(gA1 + kk, lA + 2048);
        gload16(gB0 + kk, lB);
        gload16(gB1 + kk, lB + 2048);
        __syncthreads();                       // drains vmcnt(0): tiles ready
        s8v af[4], bfr[4];
        #pragma unroll
        for (int mi = 0; mi < 4; mi++)
            af[mi] = *(const s8v*)&As[(wm + mi * 16 + l15) * 32 + l4 * 8];
        #pragma unroll
        for (int ni = 0; ni < 4; ni++)
            bfr[ni] = *(const s8v*)&Bs[(wn + ni * 16 + l15) * 32 + l4 * 8];
        #pragma unroll
        for (int mi = 0; mi < 4; mi++)
            #pragma unroll
            for (int ni = 0; ni < 4; ni++)
                acc[mi][ni] = __builtin_amdgcn_mfma_f32_16x16x32_bf16(
                    af[mi], bfr[ni], acc[mi][ni], 0, 0, 0);
    }

    float* dst = part + (size_t)s * SLICE;
    #pragma unroll
    for (int mi = 0; mi < 4; mi++) {
        #pragma unroll
        for (int ni = 0; ni < 4; ni++) {
            int col = d0 + wn + ni * 16 + l15;
            #pragma unroll
            for (int r = 0; r < 4; r++) {
                int row = i0 + wm + mi * 16 + l4 * 4 + r;
                dst[row * D_ + col] = acc[mi][ni][r];
            }
        }
    }
}

// ---------------- old fused gemm (fallback) ----------------
__launch_bounds__(256)
__global__ void gemm_kernel(const float* __restrict__ X,
                            const float* __restrict__ W,
                            float* __restrict__ part,
                            int use_atomic) {
    __shared__ __align__(16) short As[128 * LDA];
    __shared__ __align__(16) short Bs[128 * LDB];

    const int bx   = blockIdx.x;
    const int tile = bx & 15;
    const int s    = bx >> 4;
    const int i0   = (tile & 3) * 128;
    const int d0   = (tile >> 2) * 128;
    const int ks   = s * KC;
    const int ke   = min(ks + KC, V_);

    const int tid  = threadIdx.x;
    const int lane = tid & 63;
    const int wave = tid >> 6;
    const int wm   = (wave & 1) * 64;
    const int wn   = (wave >> 1) * 64;
    const int l15  = lane & 15;
    const int l4   = lane >> 4;

    const int ar   = tid >> 1;
    const int akh  = (tid & 1) * 16;
    const int bn2  = (tid & 63) * 2;
    const int bkq  = (tid >> 6) * 8;

    f4v acc[4][4];
    #pragma unroll
    for (int a = 0; a < 4; a++)
        #pragma unroll
        for (int b = 0; b < 4; b++) acc[a][b] = (f4v)0.f;

    auto stageA = [&](const float4 (&ab)[4]) {
        const float* f = (const float*)&ab[0];
        unsigned int au[8];
        #pragma unroll
        for (int p = 0; p < 8; p++)
            au[p] = pack2bf(__expf(f[2 * p]), __expf(f[2 * p + 1]));
        *(uint4*)&As[ar * LDA + akh]     = *(const uint4*)&au[0];
        *(uint4*)&As[ar * LDA + akh + 8] = *(const uint4*)&au[4];
    };
    auto stageB = [&](const float2 (&bb)[8]) {
        unsigned int r0[4], r1[4];
        #pragma unroll
        for (int p = 0; p < 4; p++) {
            r0[p] = pack2bf(bb[2 * p].x, bb[2 * p + 1].x);
            r1[p] = pack2bf(bb[2 * p].y, bb[2 * p + 1].y);
        }
        *(uint4*)&Bs[bn2 * LDB + bkq]       = *(const uint4*)&r0[0];
        *(uint4*)&Bs[(bn2 + 1) * LDB + bkq] = *(const uint4*)&r1[0];
    };
    auto domfma = [&]() {
        s8v af[4], bfr[4];
        #pragma unroll
        for (int mi = 0; mi < 4; mi++)
            af[mi] = *(const s8v*)&As[(wm + mi * 16 + l15) * LDA + l4 * 8];
        #pragma unroll
        for (int ni = 0; ni < 4; ni++)
            bfr[ni] = *(const s8v*)&Bs[(wn + ni * 16 + l15) * LDB + l4 * 8];
        #pragma unroll
        for (int mi = 0; mi < 4; mi++)
            #pragma unroll
            for (int ni = 0; ni < 4; ni++)
                acc[mi][ni] = __builtin_amdgcn_mfma_f32_16x16x32_bf16(
                    af[mi], bfr[ni], acc[mi][ni], 0, 0, 0);
    };
    auto issue = [&](float4 (&ab)[4], float2 (&bb)[8], const float* ap, const float* bp) {
        #pragma unroll
        for (int q = 0; q < 4; q++) ab[q] = *(const float4*)(ap + q * 4);
        #pragma unroll
        for (int j = 0; j < 8; j++) bb[j] = *(const float2*)(bp + (size_t)j * D_);
    };

    if (ks + KC <= V_) {
        const float* ap = X + (size_t)(i0 + ar) * V_ + ks + akh;
        const float* bp = W + d0 + bn2 + (size_t)(ks + bkq) * D_;
        float4 a0[4], a1[4];
        float2 b0[8], b1[8];
        issue(a0, b0, ap, bp);
        #pragma unroll 1
        for (int it = 0; it < NIT; it += 2) {
            ap += BK; bp += (size_t)BK * D_;
            if (it + 1 < NIT) issue(a1, b1, ap, bp);
            sync_lds();
            stageA(a0); stageB(b0);
            sync_lds();
            domfma();

            ap += BK; bp += (size_t)BK * D_;
            if (it + 2 < NIT) issue(a0, b0, ap, bp);
            sync_lds();
            stageA(a1); stageB(b1);
            sync_lds();
            domfma();
        }
    } else {
        const float* Abase = X + (size_t)(i0 + ar) * V_;
        const float* Bbase = W + d0 + bn2;
        for (int k0 = ks; k0 < ke; k0 += BK) {
            float4 ab[4];
            float2 bb[8];
            #pragma unroll
            for (int q = 0; q < 4; q++) {
                int gk = min(k0 + akh + q * 4, V_ - 4);
                ab[q] = *(const float4*)(Abase + gk);
            }
            #pragma unroll
            for (int j = 0; j < 8; j++) {
                int gk = min(k0 + bkq + j, V_ - 1);
                bb[j] = *(const float2*)(Bbase + (size_t)gk * D_);
            }
            sync_lds();
            {
                unsigned int au[8];
                const float* f = (const float*)&ab[0];
                #pragma unroll
                for (int p = 0; p < 8; p++) {
                    int g0 = k0 + akh + 2 * p;
                    float e0 = (g0     < ke) ? __expf(f[2 * p])     : 0.f;
                    float e1 = (g0 + 1 < ke) ? __expf(f[2 * p + 1]) : 0.f;
                    au[p] = pack2bf(e0, e1);
                }
                *(uint4*)&As[ar * LDA + akh]     = *(const uint4*)&au[0];
                *(uint4*)&As[ar * LDA + akh + 8] = *(const uint4*)&au[4];
            }
            {
                unsigned int r0[4], r1[4];
                #pragma unroll
                for (int p = 0; p < 4; p++) {
                    int g0 = k0 + bkq + 2 * p;
                    float x0 = (g0     < ke) ? bb[2 * p].x     : 0.f;
                    float x1 = (g0 + 1 < ke) ? bb[2 * p + 1].x : 0.f;
                    float y0 = (g0     < ke) ? bb[2 * p].y     : 0.f;
                    float y1 = (g0 + 1 < ke) ? bb[2 * p + 1].y : 0.f;
                    r0[p] = pack2bf(x0, x1);
                    r1[p] = pack2bf(y0, y1);
                }
                *(uint4*)&Bs[bn2 * LDB + bkq]       = *(const uint4*)&r0[0];
                *(uint4*)&Bs[(bn2 + 1) * LDB + bkq] = *(const uint4*)&r1[0];
            }
            sync_lds();
            domfma();
        }
    }

    float* dst = part + (use_atomic ? 0 : (size_t)s * SLICE);
    #pragma unroll
    for (int mi = 0; mi < 4; mi++) {
        #pragma unroll
        for (int ni = 0; ni < 4; ni++) {
            int col = d0 + wn + ni * 16 + l15;
            #pragma unroll
            for (int r = 0; r < 4; r++) {
                int row = i0 + wm + mi * 16 + l4 * 4 + r;
                if (use_atomic) atomicAdd(&dst[row * D_ + col], acc[mi][ni][r]);
                else            dst[row * D_ + col] = acc[mi][ni][r];
            }
        }
    }
}

// ---------------- ot: reduce slices + mean_i cos(pred_i, W[trg_i]) ----------------
__global__ void ot_kernel(const float* __restrict__ part,
                          const float* __restrict__ W,
                          const int* __restrict__ trg,
                          float* __restrict__ acc,
                          int nsl) {
    int wave = threadIdx.x >> 6, lane = threadIdx.x & 63;
    int row  = blockIdx.x * 4 + wave;
    const size_t off = (size_t)row * D_ + lane * 8;

    float4 p0 = {0, 0, 0, 0}, p1 = {0, 0, 0, 0};
    for (int s = 0; s < nsl; s++) {
        const float4* ps = (const float4*)(part + (size_t)s * SLICE + off);
        float4 q0 = ps[0], q1 = ps[1];
        p0.x += q0.x; p0.y += q0.y; p0.z += q0.z; p0.w += q0.w;
        p1.x += q1.x; p1.y += q1.y; p1.z += q1.z; p1.w += q1.w;
    }
    const float4* t4 = (const float4*)(W + (size_t)trg[row] * D_ + lane * 8);
    float4 t0 = t4[0], t1 = t4[1];

    float dot = p0.x * t0.x + p0.y * t0.y + p0.z * t0.z + p0.w * t0.w
              + p1.x * t1.x + p1.y * t1.y + p1.z * t1.z + p1.w * t1.w;
    float nn  = p0.x * p0.x + p0.y * p0.y + p0.z * p0.z + p0.w * p0.w
              + p1.x * p1.x + p1.y * p1.y + p1.z * p1.z + p1.w * p1.w;
    float tt  = t0.x * t0.x + t0.y * t0.y + t0.z * t0.z + t0.w * t0.w
              + t1.x * t1.x + t1.y * t1.y + t1.z * t1.z + t1.w * t1.w;

    dot = wave_reduce(dot); nn = wave_reduce(nn); tt = wave_reduce(tt);
    if (lane == 0)
        atomicAdd(&acc[4], (dot / sqrtf(nn * tt)) * (1.0f / (float)NROWS));
}

// ---------------- finalize ----------------
__global__ void finalize_kernel(const float* __restrict__ acc, float* __restrict__ out) {
    if (threadIdx.x == 0)
        out[0] = -acc[0] / acc[1] + acc[2] / acc[3] + GAMMA2_ + acc[4];
}

extern "C" void kernel_launch(void* const* d_in, const int* in_sizes, int n_in,
                              void* d_out, int out_size, void* d_ws, size_t ws_size,
                              hipStream_t stream) {
    const float* output_mle = (const float*)d_in[0];
    const float* attn       = (const float*)d_in[1];
    const float* cover      = (const float*)d_in[2];
    const int*   trg        = (const int*)d_in[3];
    const int*   dec_mask   = (const int*)d_in[4];
    const int*   dec_len    = (const int*)d_in[5];
    const float* W          = (const float*)d_in[6];
    float* out  = (float*)d_out;
    float* acc  = (float*)d_ws;

    const bool newpath = (ws_size >= NEED_NEW);   // constant across calls: graph-safe

    if (newpath) {
        unsigned short* Xb = (unsigned short*)((char*)d_ws + ACC_BYTES);
        unsigned short* Wt = (unsigned short*)((char*)d_ws + ACC_BYTES + XB_BYTES);
        float* part2 = (float*)((char*)d_ws + ACC_BYTES + XB_BYTES + WT_BYTES);
        hipMemsetAsync(d_ws, 0, ACC_BYTES, stream);
        prep_kernel<<<NXB + NWB + 65, 256, 0, stream>>>(
            output_mle, W, attn, cover, trg, dec_mask, dec_len, acc, Xb, Wt);
        gemm2_kernel<<<16 * SPLITK2, 256, 0, stream>>>(Xb, Wt, part2);
        ot_kernel<<<NROWS / 4, 256, 0, stream>>>(part2, W, trg, acc, SPLITK2);
        finalize_kernel<<<1, 64, 0, stream>>>(acc, out);
    } else {
        float* part = acc + WS_PART_OFF;
        const size_t need = (size_t)WS_PART_OFF * 4 + (size_t)SPLITK * SLICE * 4;
        const bool partial = (ws_size >= need);
        if (partial) {
            hipMemsetAsync(d_ws, 0, WS_PART_OFF * sizeof(float), stream);
        } else {
            hipMemsetAsync(d_ws, 0, (WS_PART_OFF + SLICE) * sizeof(float), stream);
        }
        misc_kernel<<<65, 256, 0, stream>>>(output_mle, attn, cover, trg, dec_mask, dec_len, acc);
        gemm_kernel<<<16 * SPLITK, 256, 0, stream>>>(output_mle, W, part, partial ? 0 : 1);
        ot_kernel<<<NROWS / 4, 256, 0, stream>>>(part, W, trg, acc, partial ? SPLITK : 1);
        finalize_kernel<<<1, 64, 0, stream>>>(acc, out);
    }
}